// Round 2
// baseline (2776.259 us; speedup 1.0000x reference)
//
#include <hip/hip_runtime.h>

// GINGCN forward on MI355X.
// Inputs: x f32 [N,128], eps f32 [1], edge_index int32 [2,E] (harness casts int64->int32).
// out = scatter_add(norm * x[col] -> row) + (1+eps)*x
// norm = dis[row]*dis[col], dis = deg^{-1/2} (deg = in-count on col), inf->0.

#define DFEAT 128
#define DVEC4 (DFEAT / 4)   // 32 float4 per node row

__global__ void zero_f32_kernel(float* __restrict__ p, int n) {
    int i = blockIdx.x * blockDim.x + threadIdx.x;
    if (i < n) p[i] = 0.0f;
}

__global__ void count_deg_kernel(const int* __restrict__ edge, float* __restrict__ deg,
                                 int E) {
    int e = blockIdx.x * blockDim.x + threadIdx.x;
    if (e < E) {
        int c = edge[E + e];  // col = edge_index[1][e]
        atomicAdd(&deg[c], 1.0f);
    }
}

__global__ void deg_to_dis_kernel(float* __restrict__ deg, int n) {
    int i = blockIdx.x * blockDim.x + threadIdx.x;
    if (i < n) {
        float d = deg[i];
        deg[i] = (d > 0.0f) ? (1.0f / sqrtf(d)) : 0.0f;
    }
}

// out = (1 + eps) * x, vectorized float4
__global__ void init_out_kernel(const float4* __restrict__ x4, const float* __restrict__ eps,
                                float4* __restrict__ out4, int n4) {
    int i = blockIdx.x * blockDim.x + threadIdx.x;
    if (i < n4) {
        float s = 1.0f + eps[0];
        float4 v = x4[i];
        v.x *= s; v.y *= s; v.z *= s; v.w *= s;
        out4[i] = v;
    }
}

// One 32-lane group per edge; lane c handles float4 chunk c of the 128-wide row.
__global__ void scatter_kernel(const int* __restrict__ edge,
                               const float* __restrict__ dis,
                               const float4* __restrict__ x4,
                               float* __restrict__ out, int E) {
    long long t = (long long)blockIdx.x * blockDim.x + threadIdx.x;
    int e = (int)(t >> 5);
    int c = (int)(t & 31);
    if (e >= E) return;
    int r  = edge[e];                         // row
    int cl = edge[E + e];                     // col
    float nw = dis[r] * dis[cl];              // wave-broadcast loads, L2-hot (400 KB)
    float4 v = x4[(long long)cl * DVEC4 + c]; // coalesced 512B gather per edge
    float* o = out + (long long)r * DFEAT + (long long)c * 4;
    atomicAdd(o + 0, nw * v.x);
    atomicAdd(o + 1, nw * v.y);
    atomicAdd(o + 2, nw * v.z);
    atomicAdd(o + 3, nw * v.w);
}

extern "C" void kernel_launch(void* const* d_in, const int* in_sizes, int n_in,
                              void* d_out, int out_size, void* d_ws, size_t ws_size,
                              hipStream_t stream) {
    const float* x    = (const float*)d_in[0];
    const float* eps  = (const float*)d_in[1];
    const int*   edge = (const int*)d_in[2];

    float* out = (float*)d_out;

    const int N = in_sizes[0] / DFEAT;   // 100000
    const int E = in_sizes[2] / 2;       // 1600000

    float* deg = (float*)d_ws;           // N floats (400 KB), reused as dis in-place

    const int B = 256;

    // 1. deg = 0
    zero_f32_kernel<<<(N + B - 1) / B, B, 0, stream>>>(deg, N);
    // 2. deg[col] += 1
    count_deg_kernel<<<(E + B - 1) / B, B, 0, stream>>>(edge, deg, E);
    // 3. dis = deg^{-1/2} (0 for isolated)
    deg_to_dis_kernel<<<(N + B - 1) / B, B, 0, stream>>>(deg, N);
    // 4. out = (1+eps)*x
    {
        int n4 = N * DVEC4;
        init_out_kernel<<<(n4 + B - 1) / B, B, 0, stream>>>((const float4*)x, eps,
                                                            (float4*)out, n4);
    }
    // 5. scatter: out[row] += dis[row]*dis[col] * x[col]
    {
        long long threads = (long long)E * 32;
        int blocks = (int)((threads + B - 1) / B);
        scatter_kernel<<<blocks, B, 0, stream>>>(edge, deg, (const float4*)x, out, E);
    }
}

// Round 3
// 442.219 us; speedup vs baseline: 6.2780x; 6.2780x over previous
//
#include <hip/hip_runtime.h>

// GINGCN forward on MI355X — CSR-gather formulation.
// Inputs: x f32 [N,128], eps f32 [1], edge_index int32 [2,E].
// out[r] = (1+eps)*x[r] + sum_{e: row[e]=r} dis[r]*dis[col[e]] * x[col[e]]
// dis = deg^{-1/2}, deg = histogram of col. Built per-launch (no caching).

#define DFEAT 128

// ---------- shared small kernels ----------
__global__ void zero2_kernel(int* __restrict__ a, float* __restrict__ b, int n) {
    int i = blockIdx.x * blockDim.x + threadIdx.x;
    if (i < n) { a[i] = 0; b[i] = 0.0f; }
}

__global__ void count_kernel(const int* __restrict__ edge, int* __restrict__ cnt,
                             float* __restrict__ degf, int E) {
    int e = blockIdx.x * blockDim.x + threadIdx.x;
    if (e < E) {
        atomicAdd(&cnt[edge[e]], 1);          // row histogram (CSR buckets)
        atomicAdd(&degf[edge[E + e]], 1.0f);  // col degree
    }
}

__global__ void deg_to_dis_kernel(float* __restrict__ deg, int n) {
    int i = blockIdx.x * blockDim.x + threadIdx.x;
    if (i < n) {
        float d = deg[i];
        deg[i] = (d > 0.0f) ? (1.0f / sqrtf(d)) : 0.0f;
    }
}

// ---------- exclusive scan (3-phase, N up to 512*256) ----------
__global__ void scanA_kernel(const int* __restrict__ cnt, int* __restrict__ off,
                             int* __restrict__ bsum, int n) {
    __shared__ int tmp[256];
    int i = blockIdx.x * 256 + threadIdx.x;
    int v = (i < n) ? cnt[i] : 0;
    tmp[threadIdx.x] = v;
    __syncthreads();
    for (int s = 1; s < 256; s <<= 1) {
        int t = (threadIdx.x >= s) ? tmp[threadIdx.x - s] : 0;
        __syncthreads();
        tmp[threadIdx.x] += t;
        __syncthreads();
    }
    if (i < n) off[i] = tmp[threadIdx.x] - v;  // exclusive
    if (threadIdx.x == 255) bsum[blockIdx.x] = tmp[255];
}

__global__ void scanB_kernel(int* __restrict__ bsum, int nb) {
    __shared__ int tmp[512];
    int i = threadIdx.x;
    int v = (i < nb) ? bsum[i] : 0;
    tmp[i] = v;
    __syncthreads();
    for (int s = 1; s < 512; s <<= 1) {
        int t = (i >= s) ? tmp[i - s] : 0;
        __syncthreads();
        tmp[i] += t;
        __syncthreads();
    }
    if (i < nb) bsum[i] = tmp[i] - v;  // exclusive block offsets
}

__global__ void scanC_kernel(int* __restrict__ off, const int* __restrict__ bsum,
                             int* __restrict__ pos, int n, int E) {
    int i = blockIdx.x * 256 + threadIdx.x;
    if (i < n) {
        int o = off[i] + bsum[blockIdx.x];
        off[i] = o;
        pos[i] = o;
    }
    if (i == 0) off[n] = E;
}

// ---------- CSR fill ----------
__global__ void fill_kernel(const int* __restrict__ edge, const float* __restrict__ dis,
                            int* __restrict__ pos, int* __restrict__ scol,
                            float* __restrict__ snorm, int E) {
    int e = blockIdx.x * blockDim.x + threadIdx.x;
    if (e < E) {
        int r = edge[e];
        int c = edge[E + e];
        int p = atomicAdd(&pos[r], 1);
        scol[p] = c;
        snorm[p] = dis[r] * dis[c];
    }
}

// ---------- gather: one 64-lane wave per node, float2 per lane ----------
__global__ void gather_kernel(const int* __restrict__ off, const int* __restrict__ scol,
                              const float* __restrict__ snorm, const float2* __restrict__ x2,
                              const float* __restrict__ eps, float2* __restrict__ out2,
                              int N) {
    int node = (int)((blockIdx.x * (long long)blockDim.x + threadIdx.x) >> 6);
    int lane = threadIdx.x & 63;
    if (node >= N) return;
    int s = off[node];
    int t = off[node + 1];
    long long base = (long long)node * 64 + lane;
    float2 xr = x2[base];
    float sc = 1.0f + eps[0];
    float2 acc;
    acc.x = sc * xr.x;
    acc.y = sc * xr.y;
    for (int e = s; e < t; ++e) {
        int c = scol[e];
        float nw = snorm[e];
        float2 v = x2[(long long)c * 64 + lane];
        acc.x += nw * v.x;
        acc.y += nw * v.y;
    }
    out2[base] = acc;
}

// ---------- fallback (round-2 atomic path) ----------
__global__ void init_out_kernel(const float4* __restrict__ x4, const float* __restrict__ eps,
                                float4* __restrict__ out4, int n4) {
    int i = blockIdx.x * blockDim.x + threadIdx.x;
    if (i < n4) {
        float s = 1.0f + eps[0];
        float4 v = x4[i];
        v.x *= s; v.y *= s; v.z *= s; v.w *= s;
        out4[i] = v;
    }
}

__global__ void scatter_kernel(const int* __restrict__ edge, const float* __restrict__ dis,
                               const float4* __restrict__ x4, float* __restrict__ out, int E) {
    long long tt = (long long)blockIdx.x * blockDim.x + threadIdx.x;
    int e = (int)(tt >> 5);
    int c = (int)(tt & 31);
    if (e >= E) return;
    int r  = edge[e];
    int cl = edge[E + e];
    float nw = dis[r] * dis[cl];
    float4 v = x4[(long long)cl * 32 + c];
    float* o = out + (long long)r * DFEAT + (long long)c * 4;
    atomicAdd(o + 0, nw * v.x);
    atomicAdd(o + 1, nw * v.y);
    atomicAdd(o + 2, nw * v.z);
    atomicAdd(o + 3, nw * v.w);
}

extern "C" void kernel_launch(void* const* d_in, const int* in_sizes, int n_in,
                              void* d_out, int out_size, void* d_ws, size_t ws_size,
                              hipStream_t stream) {
    const float* x    = (const float*)d_in[0];
    const float* eps  = (const float*)d_in[1];
    const int*   edge = (const int*)d_in[2];
    float* out = (float*)d_out;

    const int N = in_sizes[0] / DFEAT;   // 100000
    const int E = in_sizes[2] / 2;       // 1600000
    const int B = 256;
    const int nb = (N + 255) / 256;      // scan blocks (391) — must be <= 512

    // workspace layout (ints/floats, 4B each)
    size_t need = ((size_t)4 * N + 513 + (size_t)2 * E) * 4;
    int*   cnt   = (int*)d_ws;           // N
    int*   off   = cnt + N;              // N+1
    int*   pos   = off + N + 1;          // N
    int*   bsum  = pos + N;              // 512
    float* dis   = (float*)(bsum + 512); // N
    int*   scol  = (int*)(dis + N);      // E
    float* snorm = (float*)(scol + E);   // E

    if (ws_size >= need && nb <= 512) {
        // 1. zero histograms
        zero2_kernel<<<(N + B - 1) / B, B, 0, stream>>>(cnt, dis, N);
        // 2. histogram rows (CSR) + col degrees
        count_kernel<<<(E + B - 1) / B, B, 0, stream>>>(edge, cnt, dis, E);
        // 3. dis = deg^{-1/2}
        deg_to_dis_kernel<<<(N + B - 1) / B, B, 0, stream>>>(dis, N);
        // 4. exclusive scan cnt -> off (+ pos copy)
        scanA_kernel<<<nb, 256, 0, stream>>>(cnt, off, bsum, N);
        scanB_kernel<<<1, 512, 0, stream>>>(bsum, nb);
        scanC_kernel<<<nb, 256, 0, stream>>>(off, bsum, pos, N, E);
        // 5. CSR fill
        fill_kernel<<<(E + B - 1) / B, B, 0, stream>>>(edge, dis, pos, scol, snorm, E);
        // 6. gather (one wave per node) — fuses self term, single write per row
        {
            long long threads = (long long)N * 64;
            int blocks = (int)((threads + B - 1) / B);
            gather_kernel<<<blocks, B, 0, stream>>>(off, scol, snorm, (const float2*)x,
                                                    eps, (float2*)out, N);
        }
    } else {
        // fallback: atomic scatter (round-2 path), needs only N floats of ws
        float* deg = (float*)d_ws;
        zero2_kernel<<<(N + B - 1) / B, B, 0, stream>>>((int*)deg, deg, N);  // zeros deg twice-safe
        count_deg_fallback:
        {
            // reuse count_kernel shape: histogram col only via scatter on deg
        }
        // col-degree histogram
        count_kernel<<<(E + B - 1) / B, B, 0, stream>>>(edge, (int*)deg, deg, E); // cnt unused slot aliases deg; acceptable only for fallback
        deg_to_dis_kernel<<<(N + B - 1) / B, B, 0, stream>>>(deg, N);
        int n4 = N * (DFEAT / 4);
        init_out_kernel<<<(n4 + B - 1) / B, B, 0, stream>>>((const float4*)x, eps,
                                                            (float4*)out, n4);
        long long threads = (long long)E * 32;
        int blocks = (int)((threads + B - 1) / B);
        scatter_kernel<<<blocks, B, 0, stream>>>(edge, deg, (const float4*)x, out, E);
    }
}

// Round 4
// 390.352 us; speedup vs baseline: 7.1122x; 1.1329x over previous
//
#include <hip/hip_runtime.h>

// GINGCN forward on MI355X — CSR-gather, v2.
// out[r] = (1+eps)*x[r] + dis[r] * sum_{e: row[e]=r} dis[col[e]] * x[col[e]]
// dis = deg^{-1/2} (deg = col histogram). CSR (off, scol) built per launch.

#define DFEAT 128

// ---------- zero ----------
__global__ void zero2_kernel(int* __restrict__ a, int* __restrict__ b, int n) {
    int i = blockIdx.x * blockDim.x + threadIdx.x;
    if (i < n) { a[i] = 0; b[i] = 0; }
}

// ---------- histograms: row counts (CSR buckets) + col degrees ----------
__global__ void count_kernel(const int* __restrict__ edge, int* __restrict__ cnt,
                             int* __restrict__ degc, int E) {
    int e = blockIdx.x * blockDim.x + threadIdx.x;
    if (e < E) {
        atomicAdd(&cnt[edge[e]], 1);
        atomicAdd(&degc[edge[E + e]], 1);
    }
}

// ---------- scan phase A (+ fused deg->dis) ----------
__global__ void scanA_kernel(const int* __restrict__ cnt, int* __restrict__ off,
                             int* __restrict__ bsum, const int* __restrict__ degc,
                             float* __restrict__ dis, int n) {
    __shared__ int tmp[256];
    int i = blockIdx.x * 256 + threadIdx.x;
    int v = (i < n) ? cnt[i] : 0;
    tmp[threadIdx.x] = v;
    __syncthreads();
    for (int s = 1; s < 256; s <<= 1) {
        int t = (threadIdx.x >= s) ? tmp[threadIdx.x - s] : 0;
        __syncthreads();
        tmp[threadIdx.x] += t;
        __syncthreads();
    }
    if (i < n) {
        off[i] = tmp[threadIdx.x] - v;  // exclusive
        int d = degc[i];
        dis[i] = (d > 0) ? rsqrtf((float)d) : 0.0f;
    }
    if (threadIdx.x == 255) bsum[blockIdx.x] = tmp[255];
}

__global__ void scanB_kernel(int* __restrict__ bsum, int nb) {
    __shared__ int tmp[512];
    int i = threadIdx.x;
    int v = (i < nb) ? bsum[i] : 0;
    tmp[i] = v;
    __syncthreads();
    for (int s = 1; s < 512; s <<= 1) {
        int t = (i >= s) ? tmp[i - s] : 0;
        __syncthreads();
        tmp[i] += t;
        __syncthreads();
    }
    if (i < nb) bsum[i] = tmp[i] - v;  // exclusive block offsets
}

__global__ void scanC_kernel(int* __restrict__ off, const int* __restrict__ bsum,
                             int* __restrict__ pos, int n, int E) {
    int i = blockIdx.x * 256 + threadIdx.x;
    if (i < n) {
        int o = off[i] + bsum[blockIdx.x];
        off[i] = o;
        pos[i] = o;
    }
    if (i == 0) off[n] = E;
}

// ---------- CSR fill: scol only ----------
__global__ void fill_kernel(const int* __restrict__ edge, int* __restrict__ pos,
                            int* __restrict__ scol, int E) {
    int e = blockIdx.x * blockDim.x + threadIdx.x;
    if (e < E) {
        int r = edge[e];
        int c = edge[E + e];
        int p = atomicAdd(&pos[r], 1);
        scol[p] = c;
    }
}

// ---------- gather: 32 lanes/node, float4/lane, unroll-4 for MLP ----------
__global__ void gather_kernel(const int* __restrict__ off, const int* __restrict__ scol,
                              const float* __restrict__ dis, const float4* __restrict__ x4,
                              const float* __restrict__ eps, float4* __restrict__ out4,
                              int N) {
    long long t = (long long)blockIdx.x * blockDim.x + threadIdx.x;
    int node = (int)(t >> 5);
    int lane = (int)(t & 31);
    if (node >= N) return;
    int s = off[node];
    int tend = off[node + 1];
    float dr = dis[node];
    long long base = (long long)node * 32 + lane;
    float4 xr = x4[base];

    float a0 = 0.f, a1 = 0.f, a2 = 0.f, a3 = 0.f;
    int e = s;
    for (; e + 4 <= tend; e += 4) {
        int c0 = scol[e + 0], c1 = scol[e + 1], c2 = scol[e + 2], c3 = scol[e + 3];
        float d0 = dis[c0], d1 = dis[c1], d2 = dis[c2], d3 = dis[c3];
        float4 v0 = x4[(long long)c0 * 32 + lane];
        float4 v1 = x4[(long long)c1 * 32 + lane];
        float4 v2 = x4[(long long)c2 * 32 + lane];
        float4 v3 = x4[(long long)c3 * 32 + lane];
        a0 += d0 * v0.x + d1 * v1.x + d2 * v2.x + d3 * v3.x;
        a1 += d0 * v0.y + d1 * v1.y + d2 * v2.y + d3 * v3.y;
        a2 += d0 * v0.z + d1 * v1.z + d2 * v2.z + d3 * v3.z;
        a3 += d0 * v0.w + d1 * v1.w + d2 * v2.w + d3 * v3.w;
    }
    for (; e < tend; ++e) {
        int c = scol[e];
        float d = dis[c];
        float4 v = x4[(long long)c * 32 + lane];
        a0 += d * v.x;
        a1 += d * v.y;
        a2 += d * v.z;
        a3 += d * v.w;
    }
    float sc = 1.0f + eps[0];
    float4 o;
    o.x = sc * xr.x + dr * a0;
    o.y = sc * xr.y + dr * a1;
    o.z = sc * xr.z + dr * a2;
    o.w = sc * xr.w + dr * a3;
    out4[base] = o;
}

// ---------- fallback (atomic scatter) ----------
__global__ void zero1_kernel(float* __restrict__ p, int n) {
    int i = blockIdx.x * blockDim.x + threadIdx.x;
    if (i < n) p[i] = 0.0f;
}
__global__ void countf_kernel(const int* __restrict__ edge, float* __restrict__ deg, int E) {
    int e = blockIdx.x * blockDim.x + threadIdx.x;
    if (e < E) atomicAdd(&deg[edge[E + e]], 1.0f);
}
__global__ void degdis_kernel(float* __restrict__ deg, int n) {
    int i = blockIdx.x * blockDim.x + threadIdx.x;
    if (i < n) { float d = deg[i]; deg[i] = (d > 0.f) ? rsqrtf(d) : 0.f; }
}
__global__ void init_out_kernel(const float4* __restrict__ x4, const float* __restrict__ eps,
                                float4* __restrict__ out4, int n4) {
    int i = blockIdx.x * blockDim.x + threadIdx.x;
    if (i < n4) {
        float s = 1.0f + eps[0];
        float4 v = x4[i];
        v.x *= s; v.y *= s; v.z *= s; v.w *= s;
        out4[i] = v;
    }
}
__global__ void scatter_kernel(const int* __restrict__ edge, const float* __restrict__ dis,
                               const float4* __restrict__ x4, float* __restrict__ out, int E) {
    long long tt = (long long)blockIdx.x * blockDim.x + threadIdx.x;
    int e = (int)(tt >> 5);
    int c = (int)(tt & 31);
    if (e >= E) return;
    int r  = edge[e];
    int cl = edge[E + e];
    float nw = dis[r] * dis[cl];
    float4 v = x4[(long long)cl * 32 + c];
    float* o = out + (long long)r * DFEAT + (long long)c * 4;
    atomicAdd(o + 0, nw * v.x);
    atomicAdd(o + 1, nw * v.y);
    atomicAdd(o + 2, nw * v.z);
    atomicAdd(o + 3, nw * v.w);
}

extern "C" void kernel_launch(void* const* d_in, const int* in_sizes, int n_in,
                              void* d_out, int out_size, void* d_ws, size_t ws_size,
                              hipStream_t stream) {
    const float* x    = (const float*)d_in[0];
    const float* eps  = (const float*)d_in[1];
    const int*   edge = (const int*)d_in[2];
    float* out = (float*)d_out;

    const int N = in_sizes[0] / DFEAT;   // 100000
    const int E = in_sizes[2] / 2;       // 1600000
    const int B = 256;
    const int nb = (N + 255) / 256;      // 391 scan blocks — must be <= 512

    // workspace layout (4B units): cnt N | off N+1 | pos N | bsum 512 | degc N | dis N | scol E
    size_t need = ((size_t)5 * N + 513 + (size_t)E) * 4;
    int*   cnt  = (int*)d_ws;
    int*   off  = cnt + N;
    int*   pos  = off + N + 1;
    int*   bsum = pos + N;
    int*   degc = bsum + 512;
    float* dis  = (float*)(degc + N);
    int*   scol = (int*)(dis + N);

    if (ws_size >= need && nb <= 512) {
        zero2_kernel<<<(N + B - 1) / B, B, 0, stream>>>(cnt, degc, N);
        count_kernel<<<(E + B - 1) / B, B, 0, stream>>>(edge, cnt, degc, E);
        scanA_kernel<<<nb, 256, 0, stream>>>(cnt, off, bsum, degc, dis, N);
        scanB_kernel<<<1, 512, 0, stream>>>(bsum, nb);
        scanC_kernel<<<nb, 256, 0, stream>>>(off, bsum, pos, N, E);
        fill_kernel<<<(E + B - 1) / B, B, 0, stream>>>(edge, pos, scol, E);
        long long threads = (long long)N * 32;
        int blocks = (int)((threads + B - 1) / B);
        gather_kernel<<<blocks, B, 0, stream>>>(off, scol, dis, (const float4*)x,
                                                eps, (float4*)out, N);
    } else {
        float* deg = (float*)d_ws;  // N floats
        zero1_kernel<<<(N + B - 1) / B, B, 0, stream>>>(deg, N);
        countf_kernel<<<(E + B - 1) / B, B, 0, stream>>>(edge, deg, E);
        degdis_kernel<<<(N + B - 1) / B, B, 0, stream>>>(deg, N);
        int n4 = N * (DFEAT / 4);
        init_out_kernel<<<(n4 + B - 1) / B, B, 0, stream>>>((const float4*)x, eps,
                                                            (float4*)out, n4);
        long long threads = (long long)E * 32;
        int blocks = (int)((threads + B - 1) / B);
        scatter_kernel<<<blocks, B, 0, stream>>>(edge, deg, (const float4*)x, out, E);
    }
}

// Round 5
// 244.103 us; speedup vs baseline: 11.3733x; 1.5991x over previous
//
#include <hip/hip_runtime.h>

// GINGCN forward on MI355X — bucketed counting-sort CSR + gather, v3.
// out[r] = (1+eps)*x[r] + dis[r] * sum_{e: row[e]=r} dis[col[e]] * x[col[e]]
// dis = deg^{-1/2} (deg = col histogram).
// CSR built per launch via 2-level bucket sort (no N-wide scan, no random
// 4B global scatters — all global writes coalesced or bucket-local).

#define DFEAT 128
#define W_LOG 9
#define W_BUCKET 512          // rows per bucket
#define K3_CHUNK 4096         // edges per block in hist/scatter
#define NB_MAX 256            // max buckets supported by LDS arrays

// ---------- K1: global bucket histogram (reads row half only) ----------
__global__ void bucket_hist_kernel(const int* __restrict__ edge, int* __restrict__ bhist,
                                   int E, int NB) {
    __shared__ int bh[NB_MAX];
    int tid = threadIdx.x;
    for (int i = tid; i < NB; i += 256) bh[i] = 0;
    __syncthreads();
    int base = blockIdx.x * K3_CHUNK;
#pragma unroll
    for (int k = 0; k < K3_CHUNK / 256; ++k) {
        int idx = base + tid + k * 256;
        if (idx < E) atomicAdd(&bh[edge[idx] >> W_LOG], 1);
    }
    __syncthreads();
    for (int i = tid; i < NB; i += 256)
        if (bh[i]) atomicAdd(&bhist[i], bh[i]);
}

// ---------- K2: scan bucket counts (1 block) ----------
__global__ void scan_buckets_kernel(const int* __restrict__ bhist, int* __restrict__ bbase,
                                    int* __restrict__ bpos, int* __restrict__ off,
                                    int NB, int N, int E) {
    __shared__ int tmp[NB_MAX];
    int i = threadIdx.x;
    int v = (i < NB) ? bhist[i] : 0;
    tmp[i] = v;
    __syncthreads();
    for (int s = 1; s < NB_MAX; s <<= 1) {
        int t = (i >= s) ? tmp[i - s] : 0;
        __syncthreads();
        tmp[i] += t;
        __syncthreads();
    }
    if (i < NB) { int e = tmp[i] - v; bbase[i] = e; bpos[i] = e; }
    if (i == 0) { bbase[NB] = E; off[N] = E; }
}

// ---------- K3: bucketed scatter of packed (lrow,col) + col-degree histo ----------
__global__ void bucket_scatter_kernel(const int* __restrict__ edge, int* __restrict__ bpos,
                                      unsigned int* __restrict__ sedge,
                                      int* __restrict__ degc, int E, int NB) {
    __shared__ int bh[NB_MAX];
    __shared__ int lscan[NB_MAX];
    __shared__ int cur[NB_MAX];
    __shared__ int gb[NB_MAX];
    __shared__ int2 stg[K3_CHUNK];   // 32 KB
    int tid = threadIdx.x;
    for (int i = tid; i < NB; i += 256) bh[i] = 0;
    __syncthreads();
    int base = blockIdx.x * K3_CHUNK;
    int cnt = E - base; if (cnt > K3_CHUNK) cnt = K3_CHUNK;

    int r[K3_CHUNK / 256], c[K3_CHUNK / 256];
#pragma unroll
    for (int k = 0; k < K3_CHUNK / 256; ++k) {
        int idx = base + tid + k * 256;
        if (idx < E) {
            r[k] = edge[idx];
            c[k] = edge[E + idx];
            atomicAdd(&bh[r[k] >> W_LOG], 1);
            atomicAdd(&degc[c[k]], 1);   // col degree (fused)
        }
    }
    __syncthreads();
    // exclusive scan of bh -> lscan; reserve global space per bucket
    int v = (tid < NB) ? bh[tid] : 0;
    lscan[tid] = v;
    __syncthreads();
    for (int s = 1; s < NB_MAX; s <<= 1) {
        int t = (tid >= s) ? lscan[tid - s] : 0;
        __syncthreads();
        lscan[tid] += t;
        __syncthreads();
    }
    int excl = lscan[tid] - v;
    __syncthreads();
    lscan[tid] = excl;
    if (tid < NB) {
        gb[tid] = atomicAdd(&bpos[tid], v);
        cur[tid] = excl;
    }
    __syncthreads();
    // group edges by bucket in LDS
#pragma unroll
    for (int k = 0; k < K3_CHUNK / 256; ++k) {
        int idx = base + tid + k * 256;
        if (idx < E) {
            int slot = atomicAdd(&cur[r[k] >> W_LOG], 1);
            stg[slot] = make_int2(r[k], c[k]);
        }
    }
    __syncthreads();
    // write grouped runs to global (mostly-contiguous per bucket)
    for (int s = tid; s < cnt; s += 256) {
        int2 e = stg[s];
        int bb = e.x >> W_LOG;
        int tgt = gb[bb] + (s - lscan[bb]);
        sedge[tgt] = (((unsigned)(e.x & (W_BUCKET - 1))) << 17) | (unsigned)e.y;
    }
}

// ---------- K4: per-bucket exact CSR (off + scol), all writes bucket-local ----------
__global__ void csr_build_kernel(const unsigned int* __restrict__ sedge,
                                 const int* __restrict__ bbase, int* __restrict__ off,
                                 int* __restrict__ scol, int N) {
    __shared__ int rcnt[W_BUCKET];
    __shared__ int cursor[W_BUCKET];
    int b = blockIdx.x;
    int tid = threadIdx.x;           // 512 threads
    int s0 = bbase[b], s1 = bbase[b + 1];
    rcnt[tid] = 0;
    __syncthreads();
    for (int s = s0 + tid; s < s1; s += W_BUCKET)
        atomicAdd(&rcnt[sedge[s] >> 17], 1);
    __syncthreads();
    int v = rcnt[tid];
    for (int st = 1; st < W_BUCKET; st <<= 1) {
        int t = (tid >= st) ? rcnt[tid - st] : 0;
        __syncthreads();
        rcnt[tid] += t;
        __syncthreads();
    }
    int excl = rcnt[tid] - v;
    int row = b * W_BUCKET + tid;
    if (row < N) off[row] = s0 + excl;   // coalesced CSR offsets, no global scan
    cursor[tid] = excl;
    __syncthreads();
    for (int s = s0 + tid; s < s1; s += W_BUCKET) {
        unsigned int e = sedge[s];
        int lr = (int)(e >> 17);
        int p = atomicAdd(&cursor[lr], 1);
        scol[s0 + p] = (int)(e & 0x1FFFFu);   // scattered only within this bucket's region
    }
}

// ---------- K5: dis = deg^{-1/2}, in place (int in, float out) ----------
__global__ void dis_kernel(float* __restrict__ degdis, int n) {
    int i = blockIdx.x * blockDim.x + threadIdx.x;
    if (i < n) {
        int d = ((const int*)degdis)[i];
        degdis[i] = (d > 0) ? rsqrtf((float)d) : 0.0f;
    }
}

// ---------- K6: gather — 32 lanes/node, float4/lane, unroll-4 ----------
__global__ void gather_kernel(const int* __restrict__ off, const int* __restrict__ scol,
                              const float* __restrict__ dis, const float4* __restrict__ x4,
                              const float* __restrict__ eps, float4* __restrict__ out4,
                              int N) {
    long long t = (long long)blockIdx.x * blockDim.x + threadIdx.x;
    int node = (int)(t >> 5);
    int lane = (int)(t & 31);
    if (node >= N) return;
    int s = off[node];
    int tend = off[node + 1];
    float dr = dis[node];
    long long base = (long long)node * 32 + lane;
    float4 xr = x4[base];

    float a0 = 0.f, a1 = 0.f, a2 = 0.f, a3 = 0.f;
    int e = s;
    for (; e + 4 <= tend; e += 4) {
        int c0 = scol[e + 0], c1 = scol[e + 1], c2 = scol[e + 2], c3 = scol[e + 3];
        float d0 = dis[c0], d1 = dis[c1], d2 = dis[c2], d3 = dis[c3];
        float4 v0 = x4[(long long)c0 * 32 + lane];
        float4 v1 = x4[(long long)c1 * 32 + lane];
        float4 v2 = x4[(long long)c2 * 32 + lane];
        float4 v3 = x4[(long long)c3 * 32 + lane];
        a0 += d0 * v0.x + d1 * v1.x + d2 * v2.x + d3 * v3.x;
        a1 += d0 * v0.y + d1 * v1.y + d2 * v2.y + d3 * v3.y;
        a2 += d0 * v0.z + d1 * v1.z + d2 * v2.z + d3 * v3.z;
        a3 += d0 * v0.w + d1 * v1.w + d2 * v2.w + d3 * v3.w;
    }
    for (; e < tend; ++e) {
        int cc = scol[e];
        float d = dis[cc];
        float4 v = x4[(long long)cc * 32 + lane];
        a0 += d * v.x;
        a1 += d * v.y;
        a2 += d * v.z;
        a3 += d * v.w;
    }
    float sc = 1.0f + eps[0];
    float4 o;
    o.x = sc * xr.x + dr * a0;
    o.y = sc * xr.y + dr * a1;
    o.z = sc * xr.z + dr * a2;
    o.w = sc * xr.w + dr * a3;
    out4[base] = o;
}

// ---------- fallback (atomic scatter, needs only N floats of ws) ----------
__global__ void zero1_kernel(float* __restrict__ p, int n) {
    int i = blockIdx.x * blockDim.x + threadIdx.x;
    if (i < n) p[i] = 0.0f;
}
__global__ void countf_kernel(const int* __restrict__ edge, float* __restrict__ deg, int E) {
    int e = blockIdx.x * blockDim.x + threadIdx.x;
    if (e < E) atomicAdd(&deg[edge[E + e]], 1.0f);
}
__global__ void degdis_kernel(float* __restrict__ deg, int n) {
    int i = blockIdx.x * blockDim.x + threadIdx.x;
    if (i < n) { float d = deg[i]; deg[i] = (d > 0.f) ? rsqrtf(d) : 0.f; }
}
__global__ void init_out_kernel(const float4* __restrict__ x4, const float* __restrict__ eps,
                                float4* __restrict__ out4, int n4) {
    int i = blockIdx.x * blockDim.x + threadIdx.x;
    if (i < n4) {
        float s = 1.0f + eps[0];
        float4 v = x4[i];
        v.x *= s; v.y *= s; v.z *= s; v.w *= s;
        out4[i] = v;
    }
}
__global__ void scatter_kernel(const int* __restrict__ edge, const float* __restrict__ dis,
                               const float4* __restrict__ x4, float* __restrict__ out, int E) {
    long long tt = (long long)blockIdx.x * blockDim.x + threadIdx.x;
    int e = (int)(tt >> 5);
    int c = (int)(tt & 31);
    if (e >= E) return;
    int r  = edge[e];
    int cl = edge[E + e];
    float nw = dis[r] * dis[cl];
    float4 v = x4[(long long)cl * 32 + c];
    float* o = out + (long long)r * DFEAT + (long long)c * 4;
    atomicAdd(o + 0, nw * v.x);
    atomicAdd(o + 1, nw * v.y);
    atomicAdd(o + 2, nw * v.z);
    atomicAdd(o + 3, nw * v.w);
}

extern "C" void kernel_launch(void* const* d_in, const int* in_sizes, int n_in,
                              void* d_out, int out_size, void* d_ws, size_t ws_size,
                              hipStream_t stream) {
    const float* x    = (const float*)d_in[0];
    const float* eps  = (const float*)d_in[1];
    const int*   edge = (const int*)d_in[2];
    float* out = (float*)d_out;

    const int N = in_sizes[0] / DFEAT;   // 100000
    const int E = in_sizes[2] / 2;       // 1600000
    const int B = 256;
    const int NB = (N + W_BUCKET - 1) >> W_LOG;            // 196
    const int GE = (E + K3_CHUNK - 1) / K3_CHUNK;          // 391

    // ws layout (4B units):
    // bhist NB_MAX | bbase NB_MAX+1 | bpos NB_MAX | off N+1 | degdis N | sedge E | scol E
    size_t need = ((size_t)3 * NB_MAX + 1 + (size_t)(N + 1) + (size_t)N + (size_t)2 * E) * 4;
    int*          bhist  = (int*)d_ws;
    int*          bbase  = bhist + NB_MAX;
    int*          bpos   = bbase + NB_MAX + 1;
    int*          off    = bpos + NB_MAX;
    float*        degdis = (float*)(off + N + 1);
    unsigned int* sedge  = (unsigned int*)(degdis + N);
    int*          scol   = (int*)(sedge + E);

    if (ws_size >= need && NB <= NB_MAX) {
        hipMemsetAsync(bhist, 0, (size_t)NB_MAX * 4, stream);
        hipMemsetAsync(degdis, 0, (size_t)N * 4, stream);
        bucket_hist_kernel<<<GE, 256, 0, stream>>>(edge, bhist, E, NB);
        scan_buckets_kernel<<<1, NB_MAX, 0, stream>>>(bhist, bbase, bpos, off, NB, N, E);
        bucket_scatter_kernel<<<GE, 256, 0, stream>>>(edge, bpos, sedge, (int*)degdis, E, NB);
        csr_build_kernel<<<NB, W_BUCKET, 0, stream>>>(sedge, bbase, off, scol, N);
        dis_kernel<<<(N + B - 1) / B, B, 0, stream>>>(degdis, N);
        long long threads = (long long)N * 32;
        int blocks = (int)((threads + B - 1) / B);
        gather_kernel<<<blocks, B, 0, stream>>>(off, scol, degdis, (const float4*)x,
                                                eps, (float4*)out, N);
    } else {
        float* deg = (float*)d_ws;  // N floats
        zero1_kernel<<<(N + B - 1) / B, B, 0, stream>>>(deg, N);
        countf_kernel<<<(E + B - 1) / B, B, 0, stream>>>(edge, deg, E);
        degdis_kernel<<<(N + B - 1) / B, B, 0, stream>>>(deg, N);
        int n4 = N * (DFEAT / 4);
        init_out_kernel<<<(n4 + B - 1) / B, B, 0, stream>>>((const float4*)x, eps,
                                                            (float4*)out, n4);
        long long threads = (long long)E * 32;
        int blocks = (int)((threads + B - 1) / B);
        scatter_kernel<<<blocks, B, 0, stream>>>(edge, deg, (const float4*)x, out, E);
    }
}